// Round 2
// baseline (354.697 us; speedup 1.0000x reference)
//
#include <hip/hip_runtime.h>

// Problem shape (fixed by setup_inputs): B=4, N=16384, M=4096, C=64, K=32
static constexpr int Bn = 4;
static constexpr int Nn = 16384;
static constexpr int Mn = 4096;
static constexpr int Cn = 64;
static constexpr int Kn = 32;

static constexpr int CHUNK   = 2048;        // points staged in LDS per iteration
static constexpr int WPB     = 8;           // waves (queries) per block
static constexpr int THREADS = WPB * 64;    // 512
static constexpr int NGROUP  = CHUNK / 256; // 4-point groups per lane per chunk

// One wave handles one query m: scans all N points (LDS-staged), maintains the
// exact top-32 by key = (dist_bits<<32 | idx)  (dist asc, idx asc — matches
// jax.lax.top_k stable tie-break on -dist). List is wave-distributed: lane j
// (j<32) holds the j-th smallest key.
//
// Numerics contract (must match jax-GPU expected AND np reference bitwise):
//   xx  = (x*x + y*y) + z*z            (reduce, no FMA)
//   dot = fma(z,qz, fma(y,qy, x*qx))   (GEMM K=3 ascending-k FMA chain)
//   dist= max((xx + yy) - 2*dot, 0)    (separate elementwise ops, no FMA)
__global__ __launch_bounds__(THREADS) void knn_group(
    const float* __restrict__ P,   // [B,3,N]
    const float* __restrict__ Q,   // [B,3,M]
    const float* __restrict__ F,   // [B,C,N]
    float* __restrict__ out)       // [B,3+C,M,K]
{
#pragma clang fp contract(off)
  __shared__ float lds[4][CHUNK];  // x, y, z, xx planes

  const int tid  = threadIdx.x;
  const int lane = tid & 63;
  const int wid  = tid >> 6;
  const int bpb  = Mn / WPB;                  // blocks per batch
  const int b    = blockIdx.x / bpb;
  const int m    = (blockIdx.x % bpb) * WPB + wid;

  const float* Pb = P + (size_t)b * 3 * Nn;
  const float* Qb = Q + (size_t)b * 3 * Mn;

  const float qx = Qb[m];
  const float qy = Qb[Mn + m];
  const float qz = Qb[2 * Mn + m];
  // yy with the reference's reduce order: (qx*qx + qy*qy) + qz*qz, no FMA
  const float yyq = (qx * qx + qy * qy) + qz * qz;

  unsigned long long lst = ~0ull;   // lane j<32: sorted elem j; lanes>=32: MAX
  unsigned long long tau = ~0ull;   // current 32nd-smallest key (wave-uniform)

  for (int ch = 0; ch < Nn / CHUNK; ++ch) {
    const int n0 = ch * CHUNK;
    // ---- stage chunk into LDS: x, y, z, and xx=(x*x+y*y)+z*z ----
    {
      const int t4 = tid * 4;
      float4 vx = *(const float4*)(Pb + n0 + t4);
      float4 vy = *(const float4*)(Pb + Nn + n0 + t4);
      float4 vz = *(const float4*)(Pb + 2 * Nn + n0 + t4);
      float4 vs;
      vs.x = (vx.x * vx.x + vy.x * vy.x) + vz.x * vz.x;
      vs.y = (vx.y * vx.y + vy.y * vy.y) + vz.y * vz.y;
      vs.z = (vx.z * vx.z + vy.z * vy.z) + vz.z * vz.z;
      vs.w = (vx.w * vx.w + vy.w * vy.w) + vz.w * vz.w;
      *(float4*)&lds[0][t4] = vx;
      *(float4*)&lds[1][t4] = vy;
      *(float4*)&lds[2][t4] = vz;
      *(float4*)&lds[3][t4] = vs;
    }
    __syncthreads();

    // ---- scan: each lane 4 consecutive points per group ----
    for (int g = 0; g < NGROUP; ++g) {
      const int p = g * 256 + lane * 4;
      const float4 rx = *(const float4*)&lds[0][p];
      const float4 ry = *(const float4*)&lds[1][p];
      const float4 rz = *(const float4*)&lds[2][p];
      const float4 rs = *(const float4*)&lds[3][p];

      // dot via ascending-k FMA chain (matches GEMM K=3 on all ref backends);
      // dist via separate add/sub (no contraction), then clamp.
      float dot, d0, d1, d2, d3;
      dot = fmaf(rz.x, qz, fmaf(ry.x, qy, rx.x * qx));
      d0  = fmaxf((rs.x + yyq) - 2.0f * dot, 0.0f);
      dot = fmaf(rz.y, qz, fmaf(ry.y, qy, rx.y * qx));
      d1  = fmaxf((rs.y + yyq) - 2.0f * dot, 0.0f);
      dot = fmaf(rz.z, qz, fmaf(ry.z, qy, rx.z * qx));
      d2  = fmaxf((rs.z + yyq) - 2.0f * dot, 0.0f);
      dot = fmaf(rz.w, qz, fmaf(ry.w, qy, rx.w * qx));
      d3  = fmaxf((rs.w + yyq) - 2.0f * dot, 0.0f);

      const unsigned u0 = __float_as_uint(d0);
      const unsigned u1 = __float_as_uint(d1);
      const unsigned u2 = __float_as_uint(d2);
      const unsigned u3 = __float_as_uint(d3);
      const unsigned umin = min(min(u0, u1), min(u2, u3));

      // fast-path threshold test (u32 dist bits are monotonic for dist>=0)
      if (__any(umin <= (unsigned)(tau >> 32))) {
        const unsigned nb = (unsigned)(n0 + p);
        const unsigned long long k0 = ((unsigned long long)u0 << 32) | (nb + 0u);
        const unsigned long long k1 = ((unsigned long long)u1 << 32) | (nb + 1u);
        const unsigned long long k2 = ((unsigned long long)u2 << 32) | (nb + 2u);
        const unsigned long long k3 = ((unsigned long long)u3 << 32) | (nb + 3u);
#pragma unroll
        for (int j = 0; j < 4; ++j) {
          const unsigned long long kj = j == 0 ? k0 : j == 1 ? k1 : j == 2 ? k2 : k3;
          unsigned long long mm = __ballot(kj < tau);
          while (mm) {
            const int src = (int)__builtin_ctzll(mm);
            mm &= mm - 1;
            const unsigned long long kk = __shfl(kj, src);
            if (kk < tau) {  // re-check: tau may have tightened
              const unsigned long long below = __ballot(lst < kk);
              const int pos = (int)__popcll(below);
              const unsigned long long sh = __shfl_up(lst, 1);
              unsigned long long nv = (lane < pos) ? lst
                                   : ((lane == pos) ? kk : sh);
              if (lane < 32) lst = nv;
              tau = __shfl(lst, 31);
            }
          }
        }
      }
    }
    __syncthreads();
  }

  // ---- output: [B, 3+C, M, K] ----
  const int k   = lane & 31;
  const int idx = (int)(__shfl(lst, k) & 0xffffffffull);
  float* outb = out + (size_t)b * (3 + Cn) * Mn * Kn;

  if (lane < 32) {
    const float px = Pb[idx];
    const float py = Pb[Nn + idx];
    const float pz = Pb[2 * Nn + idx];
    outb[((size_t)0 * Mn + m) * Kn + k] = px - qx;
    outb[((size_t)1 * Mn + m) * Kn + k] = py - qy;
    outb[((size_t)2 * Mn + m) * Kn + k] = pz - qz;
  }

  const float* Fb   = F + (size_t)b * Cn * Nn;
  const int   chalf = lane >> 5;  // 64 lanes = 2 channels x 32 k
#pragma unroll 8
  for (int c0 = 0; c0 < Cn; c0 += 2) {
    const int cc = c0 + chalf;
    const float v = Fb[(size_t)cc * Nn + idx];
    outb[(((size_t)(3 + cc)) * Mn + m) * Kn + k] = v;
  }
}

extern "C" void kernel_launch(void* const* d_in, const int* in_sizes, int n_in,
                              void* d_out, int out_size, void* d_ws, size_t ws_size,
                              hipStream_t stream) {
  (void)in_sizes; (void)n_in; (void)out_size; (void)d_ws; (void)ws_size;
  const float* P = (const float*)d_in[0];
  const float* Q = (const float*)d_in[1];
  const float* F = (const float*)d_in[2];
  float* out = (float*)d_out;

  dim3 grid(Bn * Mn / WPB);   // 2048 blocks
  dim3 block(THREADS);        // 512 threads = 8 waves
  hipLaunchKernelGGL(knn_group, grid, block, 0, stream, P, Q, F, out);
}

// Round 3
// 250.397 us; speedup vs baseline: 1.4165x; 1.4165x over previous
//
#include <hip/hip_runtime.h>

// Problem shape (fixed by setup_inputs): B=4, N=16384, M=4096, C=64, K=32
static constexpr int Bn = 4;
static constexpr int Nn = 16384;
static constexpr int Mn = 4096;
static constexpr int Cn = 64;
static constexpr int Kn = 32;

static constexpr int CHUNK   = 2048;        // points staged in LDS per iteration
static constexpr int WPB     = 8;           // waves (queries) per block
static constexpr int THREADS = WPB * 64;    // 512
static constexpr int NCHUNK  = Nn / CHUNK;  // 8
static constexpr int NGROUP  = CHUNK / 256; // 8 groups of 256 points

typedef unsigned long long ull;

// lane i-1 -> lane i within the wave, lane 0 keeps old. DPP wave_shr:1 (0x138):
// VALU pipe, no DS traffic (vs __shfl_up's 2x ds_permute).
__device__ __forceinline__ ull shift_up1(ull v) {
  int lo = __builtin_amdgcn_update_dpp((int)(unsigned)v, (int)(unsigned)v,
                                       0x138, 0xf, 0xf, false);
  int hi = __builtin_amdgcn_update_dpp((int)(v >> 32), (int)(v >> 32),
                                       0x138, 0xf, 0xf, false);
  return ((ull)(unsigned)hi << 32) | (unsigned)lo;
}

__device__ __forceinline__ ull bcast64(ull v, int srclane) {
  unsigned lo = (unsigned)__builtin_amdgcn_readlane((int)(unsigned)v, srclane);
  unsigned hi = (unsigned)__builtin_amdgcn_readlane((int)(v >> 32), srclane);
  return ((ull)hi << 32) | lo;
}

// Serial exact insert of all lanes' kj that beat tau. List `lst` is sorted
// ascending across lanes 0..31 (lanes >=32 hold MAX). DS-free.
__device__ __forceinline__ void insert_keys(ull kj, ull& lst, ull& tau, int lane) {
  ull mm = __ballot(kj < tau);
  while (mm) {
    const int src = (int)__builtin_ctzll(mm);
    const ull kk = bcast64(kj, src);                    // readlane (uniform)
    const int pos = (int)__popcll(__ballot(lst < kk));  // rank of kk
    const ull sh = shift_up1(lst);
    ull nv = (lane == pos) ? kk : sh;
    nv = (lane < pos) ? lst : nv;
    if (lane < 32) lst = nv;
    tau = bcast64(lst, 31);
    mm &= mm - 1;               // clear processed lane
    mm &= __ballot(kj < tau);   // re-prune against tightened tau
  }
}

// One wave per query m. Exact top-32 by key = (dist_bits<<32 | idx) — dist asc,
// idx asc, matching jax.lax.top_k's stable tie-break on -dist.
//
// Numerics contract (matches jax-GPU expected AND np reference bitwise):
//   xx  = (x*x + y*y) + z*z            (reduce, no FMA)
//   dot = fma(z,qz, fma(y,qy, x*qx))   (GEMM K=3 ascending-k FMA chain)
//   dist= max((xx + yy) - 2*dot, 0)    (separate elementwise ops, no FMA)
__global__ __launch_bounds__(THREADS) void knn_group(
    const float* __restrict__ P,   // [B,3,N]
    const float* __restrict__ Q,   // [B,3,M]
    const float* __restrict__ F,   // [B,C,N]
    float* __restrict__ out)       // [B,3+C,M,K]
{
#pragma clang fp contract(off)
  __shared__ float lds[4][CHUNK];  // x, y, z, xx planes (32 KiB)

  const int tid  = threadIdx.x;
  const int lane = tid & 63;
  const int wid  = tid >> 6;
  const int bpb  = Mn / WPB;
  const int b    = blockIdx.x / bpb;
  const int m    = (blockIdx.x % bpb) * WPB + wid;

  const float* Pb = P + (size_t)b * 3 * Nn;
  const float* Qb = Q + (size_t)b * 3 * Mn;

  const float qx = Qb[m];
  const float qy = Qb[Mn + m];
  const float qz = Qb[2 * Mn + m];
  const float yyq = (qx * qx + qy * qy) + qz * qz;

  const int t4 = tid * 4;

  // ---- prologue: stage chunk 0 ----
  {
    float4 vx = *(const float4*)(Pb + t4);
    float4 vy = *(const float4*)(Pb + Nn + t4);
    float4 vz = *(const float4*)(Pb + 2 * Nn + t4);
    float4 vs;
    vs.x = (vx.x * vx.x + vy.x * vy.x) + vz.x * vz.x;
    vs.y = (vx.y * vx.y + vy.y * vy.y) + vz.y * vz.y;
    vs.z = (vx.z * vx.z + vy.z * vy.z) + vz.z * vz.z;
    vs.w = (vx.w * vx.w + vy.w * vy.w) + vz.w * vz.w;
    *(float4*)&lds[0][t4] = vx;
    *(float4*)&lds[1][t4] = vy;
    *(float4*)&lds[2][t4] = vz;
    *(float4*)&lds[3][t4] = vs;
  }
  __syncthreads();

  // ---- init: exact top-32 of points 0..63 via bitonic sort-64 ----
  ull lst, tau;
  {
    const float x = lds[0][lane];
    const float y = lds[1][lane];
    const float z = lds[2][lane];
    const float s = lds[3][lane];
    const float dot = fmaf(z, qz, fmaf(y, qy, x * qx));
    const float d = fmaxf((s + yyq) - 2.0f * dot, 0.0f);
    ull key = ((ull)__float_as_uint(d) << 32) | (unsigned)lane;
#pragma unroll
    for (int k = 2; k <= 64; k <<= 1) {
#pragma unroll
      for (int j = k >> 1; j > 0; j >>= 1) {
        const ull other = __shfl_xor(key, j);
        const bool keep_min = ((lane & j) == 0) == ((lane & k) == 0);
        const bool take = keep_min ? (other < key) : (other > key);
        key = take ? other : key;
      }
    }
    lst = (lane < 32) ? key : ~0ull;   // lane j<32 holds j-th smallest
    tau = bcast64(lst, 31);
  }

  // ---- main scan over chunks ----
  for (int ch = 0; ch < NCHUNK; ++ch) {
    const int n0 = ch * CHUNK;

    // prefetch next chunk into registers (hides global latency under scan)
    float4 nx, ny, nz;
    if (ch + 1 < NCHUNK) {
      nx = *(const float4*)(Pb + (n0 + CHUNK) + t4);
      ny = *(const float4*)(Pb + Nn + (n0 + CHUNK) + t4);
      nz = *(const float4*)(Pb + 2 * Nn + (n0 + CHUNK) + t4);
    }

    for (int g = 0; g < NGROUP; ++g) {
      const int p = g * 256 + lane * 4;
      const float4 rx = *(const float4*)&lds[0][p];
      const float4 ry = *(const float4*)&lds[1][p];
      const float4 rz = *(const float4*)&lds[2][p];
      const float4 rs = *(const float4*)&lds[3][p];

      float dot, d0, d1, d2, d3;
      dot = fmaf(rz.x, qz, fmaf(ry.x, qy, rx.x * qx));
      d0  = fmaxf((rs.x + yyq) - 2.0f * dot, 0.0f);
      dot = fmaf(rz.y, qz, fmaf(ry.y, qy, rx.y * qx));
      d1  = fmaxf((rs.y + yyq) - 2.0f * dot, 0.0f);
      dot = fmaf(rz.z, qz, fmaf(ry.z, qy, rx.z * qx));
      d2  = fmaxf((rs.z + yyq) - 2.0f * dot, 0.0f);
      dot = fmaf(rz.w, qz, fmaf(ry.w, qy, rx.w * qx));
      d3  = fmaxf((rs.w + yyq) - 2.0f * dot, 0.0f);

      unsigned u0 = __float_as_uint(d0);
      unsigned u1 = __float_as_uint(d1);
      unsigned u2 = __float_as_uint(d2);
      unsigned u3 = __float_as_uint(d3);

      // points 0..63 were consumed by the init sort — mask them out
      if (ch == 0 && g == 0 && lane < 16) {
        u0 = u1 = u2 = u3 = 0xFFFFFFFFu;
      }

      const unsigned umin = min(min(u0, u1), min(u2, u3));
      const unsigned tau_hi = (unsigned)(tau >> 32);
      if (__any(umin <= tau_hi)) {
        const unsigned nb = (unsigned)(n0 + p);
        const ull k0 = ((ull)u0 << 32) | (nb + 0u);
        const ull k1 = ((ull)u1 << 32) | (nb + 1u);
        const ull k2 = ((ull)u2 << 32) | (nb + 2u);
        const ull k3 = ((ull)u3 << 32) | (nb + 3u);
        insert_keys(k0, lst, tau, lane);
        insert_keys(k1, lst, tau, lane);
        insert_keys(k2, lst, tau, lane);
        insert_keys(k3, lst, tau, lane);
      }
    }
    __syncthreads();

    if (ch + 1 < NCHUNK) {
      float4 vs;
      vs.x = (nx.x * nx.x + ny.x * ny.x) + nz.x * nz.x;
      vs.y = (nx.y * nx.y + ny.y * ny.y) + nz.y * nz.y;
      vs.z = (nx.z * nx.z + ny.z * ny.z) + nz.z * nz.z;
      vs.w = (nx.w * nx.w + ny.w * ny.w) + nz.w * nz.w;
      *(float4*)&lds[0][t4] = nx;
      *(float4*)&lds[1][t4] = ny;
      *(float4*)&lds[2][t4] = nz;
      *(float4*)&lds[3][t4] = vs;
      __syncthreads();
    }
  }

  // ---- output: [B, 3+C, M, K] ----
  const int k   = lane & 31;
  const int idx = (int)(__shfl(lst, k) & 0xffffffffull);
  float* outb = out + (size_t)b * (3 + Cn) * Mn * Kn;

  if (lane < 32) {
    const float px = Pb[idx];
    const float py = Pb[Nn + idx];
    const float pz = Pb[2 * Nn + idx];
    outb[((size_t)0 * Mn + m) * Kn + k] = px - qx;
    outb[((size_t)1 * Mn + m) * Kn + k] = py - qy;
    outb[((size_t)2 * Mn + m) * Kn + k] = pz - qz;
  }

  const float* Fb = F + (size_t)b * Cn * Nn;
  const int chalf = lane >> 5;  // 64 lanes = 2 channels x 32 k
#pragma unroll 8
  for (int c0 = 0; c0 < Cn; c0 += 2) {
    const int cc = c0 + chalf;
    const float v = Fb[(size_t)cc * Nn + idx];
    outb[(((size_t)(3 + cc)) * Mn + m) * Kn + k] = v;
  }
}

extern "C" void kernel_launch(void* const* d_in, const int* in_sizes, int n_in,
                              void* d_out, int out_size, void* d_ws, size_t ws_size,
                              hipStream_t stream) {
  (void)in_sizes; (void)n_in; (void)out_size; (void)d_ws; (void)ws_size;
  const float* P = (const float*)d_in[0];
  const float* Q = (const float*)d_in[1];
  const float* F = (const float*)d_in[2];
  float* out = (float*)d_out;

  dim3 grid(Bn * Mn / WPB);   // 2048 blocks
  dim3 block(THREADS);        // 512 threads = 8 waves
  hipLaunchKernelGGL(knn_group, grid, block, 0, stream, P, Q, F, out);
}

// Round 4
// 183.261 us; speedup vs baseline: 1.9355x; 1.3663x over previous
//
#include <hip/hip_runtime.h>

// Problem shape (fixed by setup_inputs): B=4, N=16384, M=4096, C=64, K=32
static constexpr int Bn = 4;
static constexpr int Nn = 16384;
static constexpr int Mn = 4096;
static constexpr int Cn = 64;
static constexpr int Kn = 32;

static constexpr int CHUNK   = 2048;
static constexpr int WPB     = 8;
static constexpr int THREADS = WPB * 64;    // 512
static constexpr int NCHUNK  = Nn / CHUNK;  // 8
static constexpr int NGROUP  = CHUNK / 256; // 8

// Safety margin for the surrogate filter (abs, dist^2 scale). Worst-case
// rounding divergence between surrogate (yy-2s) and reference dist is
// ~1.5e-4 (values bounded ~50, ~5 roundings); 4e-3 gives ~25x margin while
// admitting only a couple of extra exact-recomputes per query.
static constexpr float EPS = 4e-3f;

typedef unsigned long long ull;

// lane i-1 -> lane i (lane 0 keeps old). DPP wave_shr:1 — VALU pipe, no DS.
__device__ __forceinline__ ull shift_up1(ull v) {
  int lo = __builtin_amdgcn_update_dpp((int)(unsigned)v, (int)(unsigned)v,
                                       0x138, 0xf, 0xf, false);
  int hi = __builtin_amdgcn_update_dpp((int)(v >> 32), (int)(v >> 32),
                                       0x138, 0xf, 0xf, false);
  return ((ull)(unsigned)hi << 32) | (unsigned)lo;
}

__device__ __forceinline__ ull bcast64(ull v, int srclane) {
  unsigned lo = (unsigned)__builtin_amdgcn_readlane((int)(unsigned)v, srclane);
  unsigned hi = (unsigned)__builtin_amdgcn_readlane((int)(v >> 32), srclane);
  return ((ull)hi << 32) | lo;
}

// Exact serial insert of all lanes' kj beating tau into the sorted lane-list.
__device__ __forceinline__ void insert_keys(ull kj, ull& lst, ull& tau, int lane) {
  ull mm = __ballot(kj < tau);
  while (mm) {
    const int src = (int)__builtin_ctzll(mm);
    const ull kk = bcast64(kj, src);
    const int pos = (int)__popcll(__ballot(lst < kk));
    const ull sh = shift_up1(lst);
    ull nv = (lane == pos) ? kk : sh;
    nv = (lane < pos) ? lst : nv;
    if (lane < 32) lst = nv;
    tau = bcast64(lst, 31);
    mm &= mm - 1;
    mm &= __ballot(kj < tau);
  }
}

// ---------------- kernel 0: F [B,C,N] -> FT [B,N,C] ----------------
__global__ __launch_bounds__(256) void transpose_f(
    const float* __restrict__ F, float* __restrict__ FT) {
  __shared__ float t[64][65];
  const int tid = threadIdx.x;
  const int bid = blockIdx.x;                 // 256 blocks
  const int xcd = bid & 7;
  const int b   = xcd >> 1;                   // 2 XCDs per batch
  const int nt  = (bid >> 3) * 2 + (xcd & 1); // 0..63
  const float* Fb = F + (size_t)b * Cn * Nn;
  float* FTb = FT + (size_t)b * Nn * Cn;
  for (int sub = 0; sub < 4; ++sub) {
    const int nbase = nt * 256 + sub * 64;
#pragma unroll
    for (int i = 0; i < 16; ++i) {
      const int c = (tid >> 6) + 4 * i;
      t[c][tid & 63] = Fb[(size_t)c * Nn + nbase + (tid & 63)];
    }
    __syncthreads();
#pragma unroll
    for (int i = 0; i < 16; ++i) {
      const int nn = (tid >> 6) + 4 * i;
      FTb[(size_t)(nbase + nn) * Cn + (tid & 63)] = t[tid & 63][nn];
    }
    __syncthreads();
  }
}

// ---------------- kernel 1: kNN + grouped gather ----------------
// Numerics contract (bit-matches jax-GPU expected AND np reference):
//   xx  = (x*x + y*y) + z*z            (reduce, no FMA)  [staged as h=-xx/2]
//   dot = fma(z,qz, fma(y,qy, x*qx))   (GEMM K=3 ascending-k FMA chain)
//   dist= max((xx + yy) - 2*dot, 0)    (separate elementwise ops, no FMA)
// Fast path uses surrogate s = fma(z,qz,fma(y,qy,fma(x,qx,h))); a point can
// belong to the top-32 only if yy-2s <= tau_d + EPS  <=>  s >= tau_f.
__global__ __launch_bounds__(THREADS, 8) void knn_group(
    const float* __restrict__ P,   // [B,3,N]
    const float* __restrict__ Q,   // [B,3,M]
    const float* __restrict__ FT,  // [B,N,C]
    float* __restrict__ out)       // [B,3+C,M,K]
{
#pragma clang fp contract(off)
  __shared__ float lds[4][CHUNK];  // x, y, z, h planes (32 KiB)

  const int tid  = threadIdx.x;
  const int lane = tid & 63;
  const int wid  = tid >> 6;
  const int bid  = blockIdx.x;          // 2048
  const int xcd  = bid & 7;
  const int b    = xcd >> 1;            // 2 XCDs per batch -> L2 locality
  const int tile = (bid >> 3) * 2 + (xcd & 1);  // 0..511
  const int m    = tile * WPB + wid;

  const float* Pb = P + (size_t)b * 3 * Nn;
  const float* Qb = Q + (size_t)b * 3 * Mn;

  const float qx = Qb[m];
  const float qy = Qb[Mn + m];
  const float qz = Qb[2 * Mn + m];
  const float yyq = (qx * qx + qy * qy) + qz * qz;

  const int t4 = tid * 4;

  // ---- stage chunk 0 ----
  {
    float4 vx = *(const float4*)(Pb + t4);
    float4 vy = *(const float4*)(Pb + Nn + t4);
    float4 vz = *(const float4*)(Pb + 2 * Nn + t4);
    float4 vh;
    vh.x = -0.5f * ((vx.x * vx.x + vy.x * vy.x) + vz.x * vz.x);
    vh.y = -0.5f * ((vx.y * vx.y + vy.y * vy.y) + vz.y * vz.y);
    vh.z = -0.5f * ((vx.z * vx.z + vy.z * vy.z) + vz.z * vz.z);
    vh.w = -0.5f * ((vx.w * vx.w + vy.w * vy.w) + vz.w * vz.w);
    *(float4*)&lds[0][t4] = vx;
    *(float4*)&lds[1][t4] = vy;
    *(float4*)&lds[2][t4] = vz;
    *(float4*)&lds[3][t4] = vh;
  }
  __syncthreads();

  // ---- init: exact top-32 of points 0..63 via bitonic sort-64 ----
  ull lst, tau;
  float tau_f;
  {
    const float x = lds[0][lane];
    const float y = lds[1][lane];
    const float z = lds[2][lane];
    const float h = lds[3][lane];
    const float xx = -2.0f * h;                       // bit-exact recover
    const float dot = fmaf(z, qz, fmaf(y, qy, x * qx));
    const float d = fmaxf((xx + yyq) - 2.0f * dot, 0.0f);
    ull key = ((ull)__float_as_uint(d) << 32) | (unsigned)lane;
#pragma unroll
    for (int k = 2; k <= 64; k <<= 1) {
#pragma unroll
      for (int j = k >> 1; j > 0; j >>= 1) {
        const ull other = __shfl_xor(key, j);
        const bool keep_min = ((lane & j) == 0) == ((lane & k) == 0);
        const bool take = keep_min ? (other < key) : (other > key);
        key = take ? other : key;
      }
    }
    lst = (lane < 32) ? key : ~0ull;
    tau = bcast64(lst, 31);
    tau_f = (yyq - __uint_as_float((unsigned)(tau >> 32)) - EPS) * 0.5f;
  }

  // ---- main scan ----
  for (int ch = 0; ch < NCHUNK; ++ch) {
    const int n0 = ch * CHUNK;

    float4 nx, ny, nz;
    if (ch + 1 < NCHUNK) {
      nx = *(const float4*)(Pb + (n0 + CHUNK) + t4);
      ny = *(const float4*)(Pb + Nn + (n0 + CHUNK) + t4);
      nz = *(const float4*)(Pb + 2 * Nn + (n0 + CHUNK) + t4);
    }

#pragma unroll
    for (int g = 0; g < NGROUP; ++g) {
      const int p = g * 256 + lane * 4;
      const float4 rx = *(const float4*)&lds[0][p];
      const float4 ry = *(const float4*)&lds[1][p];
      const float4 rz = *(const float4*)&lds[2][p];
      const float4 rh = *(const float4*)&lds[3][p];

      // surrogate: s = dot - xx/2 (3 fma/pt)
      float s0 = fmaf(rz.x, qz, fmaf(ry.x, qy, fmaf(rx.x, qx, rh.x)));
      float s1 = fmaf(rz.y, qz, fmaf(ry.y, qy, fmaf(rx.y, qx, rh.y)));
      float s2 = fmaf(rz.z, qz, fmaf(ry.z, qy, fmaf(rx.z, qx, rh.z)));
      float s3 = fmaf(rz.w, qz, fmaf(ry.w, qy, fmaf(rx.w, qx, rh.w)));

      const bool mask_init = (ch == 0) && (g == 0);
      if (mask_init && lane < 16) {   // points 0..63 consumed by init sort
        s0 = s1 = s2 = s3 = -__builtin_inff();
      }

      const float smax = fmaxf(fmaxf(s0, s1), fmaxf(s2, s3));
      if (__any(smax >= tau_f)) {
        const unsigned nb = (unsigned)(n0 + p);
#define PROC(SX, CX, CY, CZ, CH_, NOFF)                                      \
        if (__any(SX >= tau_f)) {                                            \
          const float xx = -2.0f * (CH_);                                    \
          const float dd = fmaf((CZ), qz, fmaf((CY), qy, (CX) * qx));        \
          const float d  = fmaxf((xx + yyq) - 2.0f * dd, 0.0f);              \
          ull key = ((ull)__float_as_uint(d) << 32) | (unsigned)(NOFF);      \
          if (mask_init && lane < 16) key = ~0ull;                           \
          insert_keys(key, lst, tau, lane);                                  \
          tau_f = (yyq - __uint_as_float((unsigned)(tau >> 32)) - EPS) * 0.5f; \
        }
        PROC(s0, rx.x, ry.x, rz.x, rh.x, nb + 0u)
        PROC(s1, rx.y, ry.y, rz.y, rh.y, nb + 1u)
        PROC(s2, rx.z, ry.z, rz.z, rh.z, nb + 2u)
        PROC(s3, rx.w, ry.w, rz.w, rh.w, nb + 3u)
#undef PROC
      }
    }
    __syncthreads();

    if (ch + 1 < NCHUNK) {
      float4 vh;
      vh.x = -0.5f * ((nx.x * nx.x + ny.x * ny.x) + nz.x * nz.x);
      vh.y = -0.5f * ((nx.y * nx.y + ny.y * ny.y) + nz.y * nz.y);
      vh.z = -0.5f * ((nx.z * nx.z + ny.z * ny.z) + nz.z * nz.z);
      vh.w = -0.5f * ((nx.w * nx.w + ny.w * ny.w) + nz.w * nz.w);
      *(float4*)&lds[0][t4] = nx;
      *(float4*)&lds[1][t4] = ny;
      *(float4*)&lds[2][t4] = nz;
      *(float4*)&lds[3][t4] = vh;
      __syncthreads();
    }
  }

  // ---- output: [B, 3+C, M, K] ----
  const size_t MK = (size_t)Mn * Kn;
  float* outb = out + (size_t)b * (3 + Cn) * MK;

  if (lane < 32) {
    const int idx = (int)(__shfl(lst, lane) & 0xffffffffull);
    const float px = Pb[idx];
    const float py = Pb[Nn + idx];
    const float pz = Pb[2 * Nn + idx];
    outb[0 * MK + (size_t)m * Kn + lane] = px - qx;
    outb[1 * MK + (size_t)m * Kn + lane] = py - qy;
    outb[2 * MK + (size_t)m * Kn + lane] = pz - qz;
  }

  // features: coalesced rows from FT, 64B-segment writes
  const float* FTb = FT + (size_t)b * Nn * Cn;
  const int r = lane & 15;
  const int q = lane >> 4;   // 0..3
#pragma unroll
  for (int p2 = 0; p2 < 2; ++p2) {
    const int k = p2 * 16 + r;
    const int idxk = (int)(__shfl(lst, k) & 0xffffffffull);
    const float* row = FTb + (size_t)idxk * Cn;
    float4 v[4];
#pragma unroll
    for (int i = 0; i < 4; ++i)
      v[i] = *(const float4*)(row + (q + 4 * i) * 4);
#pragma unroll
    for (int i = 0; i < 4; ++i) {
      const int c = (q + 4 * i) * 4;
      float* o = outb + (size_t)(3 + c) * MK + (size_t)m * Kn + k;
      o[0 * MK] = v[i].x;
      o[1 * MK] = v[i].y;
      o[2 * MK] = v[i].z;
      o[3 * MK] = v[i].w;
    }
  }
}

extern "C" void kernel_launch(void* const* d_in, const int* in_sizes, int n_in,
                              void* d_out, int out_size, void* d_ws, size_t ws_size,
                              hipStream_t stream) {
  (void)in_sizes; (void)n_in; (void)out_size; (void)ws_size;
  const float* P = (const float*)d_in[0];
  const float* Q = (const float*)d_in[1];
  const float* F = (const float*)d_in[2];
  float* out = (float*)d_out;
  float* FT  = (float*)d_ws;   // 4*16384*64*4 = 16.8 MB

  hipLaunchKernelGGL(transpose_f, dim3(256), dim3(256), 0, stream, F, FT);
  hipLaunchKernelGGL(knn_group, dim3(Bn * Mn / WPB), dim3(THREADS), 0, stream,
                     P, Q, FT, out);
}